// Round 6
// baseline (3399.567 us; speedup 1.0000x reference)
//
#include <hip/hip_runtime.h>

#define HID    2048
#define G3     6144   // 3*HID
#define NVOCAB 128
#define SEQ    512
#define NBLK   128
#define TAGBASE 0x5EED0000u

__device__ __forceinline__ float sigmoidf_(float x) {
  return 1.f / (1.f + __expf(-x));
}
__device__ __forceinline__ float tanhf_(float x) {
  const float ax = fabsf(x);
  const float e2 = __expf(-2.f * ax);
  return copysignf((1.f - e2) / (1.f + e2), x);
}

// ---------------------------------------------------------------------------
// Kernel 1: GI[v][j] = dot(w_ih[j,:], emb[v,:]) + b_ih[j]
// ---------------------------------------------------------------------------
__global__ __launch_bounds__(256) void gi_precompute(
    const float* __restrict__ emb,
    const float* __restrict__ w_ih,
    const float* __restrict__ b_ih,
    float* __restrict__ GI) {
  __shared__ float sE[64][33];
  __shared__ float sW[64][33];

  const int j0 = blockIdx.x * 64;
  const int v0 = blockIdx.y * 64;
  const int tid = threadIdx.x;
  const int tx = tid & 15;
  const int ty = tid >> 4;
  const int r  = tid >> 3;
  const int c4 = (tid & 7) * 4;

  float acc[4][4] = {};

  for (int k0 = 0; k0 < HID; k0 += 32) {
    __syncthreads();
    float4 eA = *(const float4*)&emb [(size_t)(v0 + r)      * HID + k0 + c4];
    float4 eB = *(const float4*)&emb [(size_t)(v0 + r + 32) * HID + k0 + c4];
    float4 wA = *(const float4*)&w_ih[(size_t)(j0 + r)      * HID + k0 + c4];
    float4 wB = *(const float4*)&w_ih[(size_t)(j0 + r + 32) * HID + k0 + c4];
    sE[r][c4+0] = eA.x; sE[r][c4+1] = eA.y; sE[r][c4+2] = eA.z; sE[r][c4+3] = eA.w;
    sE[r+32][c4+0] = eB.x; sE[r+32][c4+1] = eB.y; sE[r+32][c4+2] = eB.z; sE[r+32][c4+3] = eB.w;
    sW[r][c4+0] = wA.x; sW[r][c4+1] = wA.y; sW[r][c4+2] = wA.z; sW[r][c4+3] = wA.w;
    sW[r+32][c4+0] = wB.x; sW[r+32][c4+1] = wB.y; sW[r+32][c4+2] = wB.z; sW[r+32][c4+3] = wB.w;
    __syncthreads();

    #pragma unroll
    for (int kk = 0; kk < 32; ++kk) {
      float e0 = sE[ty*4+0][kk], e1 = sE[ty*4+1][kk];
      float e2 = sE[ty*4+2][kk], e3 = sE[ty*4+3][kk];
      float w0 = sW[tx*4+0][kk], w1 = sW[tx*4+1][kk];
      float w2 = sW[tx*4+2][kk], w3 = sW[tx*4+3][kk];
      acc[0][0] += e0*w0; acc[0][1] += e0*w1; acc[0][2] += e0*w2; acc[0][3] += e0*w3;
      acc[1][0] += e1*w0; acc[1][1] += e1*w1; acc[1][2] += e1*w2; acc[1][3] += e1*w3;
      acc[2][0] += e2*w0; acc[2][1] += e2*w1; acc[2][2] += e2*w2; acc[2][3] += e2*w3;
      acc[3][0] += e3*w0; acc[3][1] += e3*w1; acc[3][2] += e3*w2; acc[3][3] += e3*w3;
    }
  }

  #pragma unroll
  for (int a = 0; a < 4; ++a)
    #pragma unroll
    for (int b = 0; b < 4; ++b) {
      const int j = j0 + tx*4 + b;
      GI[(size_t)(v0 + ty*4 + a) * G3 + j] = acc[a][b] + b_ih[j];
    }
}

// ---------------------------------------------------------------------------
// Persistent GRU: 128 blocks x 256 threads. Each wave owns 4 hidden units
// (wid, wid+512, wid+1024, wid+1536); 12 W_hh rows pinned (256 AGPR+128 VGPR).
// Tagged fp32 exchange with s_sleep backoff + per-block rotated poll order.
// ---------------------------------------------------------------------------
__global__ __launch_bounds__(256, 1) void gru_reg(
    const float* __restrict__ GI,
    const float* __restrict__ Whh,
    const float* __restrict__ bhh,
    const int*   __restrict__ inputs,
    const float* __restrict__ wout,
    const float* __restrict__ bout,
    unsigned long long* __restrict__ bufU,   // 2 * 2048 tagged slots
    unsigned* __restrict__ done,             // (NBLK+1)*16 dwords
    float* __restrict__ out,
    const float* __restrict__ hx) {

  __shared__ int   s_inp[SEQ];
  __shared__ float s_h[HID];
  __shared__ float s_logits[2];

  const int tid  = threadIdx.x;
  const int lane = tid & 63;
  const int wv   = tid >> 6;
  const int wid  = blockIdx.x * 4 + wv;     // 0..511
  const int rot  = (blockIdx.x << 3);       // poll-order rotation
  unsigned* flag0 = done + NBLK * 16;

  for (int k = tid; k < SEQ; k += 256) s_inp[k] = inputs[k];

  // ---- preload 12 W_hh rows (384 regs/lane) ----
  float wR0[32], wR1[32], wR2[32], wR3[32];
  float wZ0[32], wZ1[32], wZ2[32], wZ3[32];
  float wN0[32], wN1[32], wN2[32], wN3[32];
  {
    #pragma unroll
    for (int q = 0; q < 4; ++q) {
      const int u = wid + (q << 9);
      const float* pr = Whh + (size_t)u * HID;
      const float* pz = Whh + (size_t)(u + HID) * HID;
      const float* pn = Whh + (size_t)(u + 2*HID) * HID;
      float* dr = q==0 ? wR0 : q==1 ? wR1 : q==2 ? wR2 : wR3;
      float* dz = q==0 ? wZ0 : q==1 ? wZ1 : q==2 ? wZ2 : wZ3;
      float* dn = q==0 ? wN0 : q==1 ? wN1 : q==2 ? wN2 : wN3;
      #pragma unroll
      for (int c = 0; c < 8; ++c) {
        const int k = c * 256 + lane * 4;
        *(float4*)&dr[c*4] = *(const float4*)&pr[k];
        *(float4*)&dz[c*4] = *(const float4*)&pz[k];
        *(float4*)&dn[c*4] = *(const float4*)&pn[k];
      }
    }
  }
  // Pin: 256 values in AGPRs (arch limit 256), 128 in VGPRs. Opaque asm
  // outputs cannot be rematerialized from memory inside the step loop.
  #pragma unroll
  for (int c = 0; c < 32; ++c) {
    asm volatile("" : "+a"(wR0[c]), "+a"(wR1[c]), "+a"(wR2[c]), "+a"(wR3[c]),
                      "+a"(wZ0[c]), "+a"(wZ1[c]), "+a"(wZ2[c]), "+a"(wZ3[c]),
                      "+v"(wN0[c]), "+v"(wN1[c]), "+v"(wN2[c]), "+v"(wN3[c]));
  }

  // per-lane gate scalars for unit q = lane&3
  const int q  = lane & 3;
  const int uq = wid + (q << 9);
  const float b_r = bhh[uq];
  const float b_z = bhh[uq + HID];
  const float b_n = bhh[uq + 2*HID];

  __syncthreads();   // s_inp ready

  float g_r, g_z, g_n;
  {
    const float* gp = GI + (size_t)s_inp[0] * G3;
    g_r = gp[uq]; g_z = gp[uq + HID]; g_n = gp[uq + 2*HID];
  }

  for (int s = 0; s < SEQ; ++s) {
    // ---- stage h (version s) into LDS ----
    if (s == 0) {
      #pragma unroll
      for (int j = 0; j < 8; ++j) s_h[j*256 + tid] = hx[j*256 + tid];
    } else {
      const unsigned wantTag = TAGBASE | (unsigned)s;
      const unsigned long long* br_ = bufU + (size_t)(s & 1) * HID;
      unsigned pending = 0xFFu;
      bool first = true;
      while (pending) {
        if (!first) __builtin_amdgcn_s_sleep(1);
        first = false;
        unsigned long long x[8];
        #pragma unroll
        for (int j = 0; j < 8; ++j)
          if (pending & (1u << j))
            x[j] = __hip_atomic_load(br_ + ((j*256 + tid + rot) & (HID-1)),
                                     __ATOMIC_RELAXED, __HIP_MEMORY_SCOPE_AGENT);
        #pragma unroll
        for (int j = 0; j < 8; ++j)
          if ((pending & (1u << j)) && (unsigned)(x[j] >> 32) == wantTag) {
            s_h[(j*256 + tid + rot) & (HID-1)] = __uint_as_float((unsigned)x[j]);
            pending &= ~(1u << j);
          }
      }
    }
    __syncthreads();

    // ---- prefetch next step's GI scalars ----
    float ng_r = g_r, ng_z = g_z, ng_n = g_n;
    if (s + 1 < SEQ) {
      const float* gp = GI + (size_t)s_inp[s+1] * G3;
      ng_r = gp[uq]; ng_z = gp[uq + HID]; ng_n = gp[uq + 2*HID];
    }

    // ---- 12 dot products: LDS h x pinned weights ----
    float r0=0.f,r1=0.f,r2=0.f,r3=0.f;
    float z0=0.f,z1=0.f,z2=0.f,z3=0.f;
    float n0=0.f,n1=0.f,n2=0.f,n3=0.f;
    #pragma unroll
    for (int c = 0; c < 8; ++c) {
      const float4 h4 = *(const float4*)&s_h[c*256 + lane*4];
      #pragma unroll
      for (int e = 0; e < 4; ++e) {
        const float hv = e==0 ? h4.x : e==1 ? h4.y : e==2 ? h4.z : h4.w;
        const int k = c*4 + e;
        r0 = fmaf(wR0[k], hv, r0); r1 = fmaf(wR1[k], hv, r1);
        r2 = fmaf(wR2[k], hv, r2); r3 = fmaf(wR3[k], hv, r3);
        z0 = fmaf(wZ0[k], hv, z0); z1 = fmaf(wZ1[k], hv, z1);
        z2 = fmaf(wZ2[k], hv, z2); z3 = fmaf(wZ3[k], hv, z3);
        n0 = fmaf(wN0[k], hv, n0); n1 = fmaf(wN1[k], hv, n1);
        n2 = fmaf(wN2[k], hv, n2); n3 = fmaf(wN3[k], hv, n3);
      }
    }

    const float hp = s_h[uq];   // previous h of this lane's unit

    #pragma unroll
    for (int m = 32; m > 0; m >>= 1) {
      r0 += __shfl_xor(r0, m); r1 += __shfl_xor(r1, m);
      r2 += __shfl_xor(r2, m); r3 += __shfl_xor(r3, m);
      z0 += __shfl_xor(z0, m); z1 += __shfl_xor(z1, m);
      z2 += __shfl_xor(z2, m); z3 += __shfl_xor(z3, m);
      n0 += __shfl_xor(n0, m); n1 += __shfl_xor(n1, m);
      n2 += __shfl_xor(n2, m); n3 += __shfl_xor(n3, m);
    }

    // ---- gates for unit q on every lane; lanes 0-3 publish ----
    const float ar = q==0 ? r0 : q==1 ? r1 : q==2 ? r2 : r3;
    const float az = q==0 ? z0 : q==1 ? z1 : q==2 ? z2 : z3;
    const float an = q==0 ? n0 : q==1 ? n1 : q==2 ? n2 : n3;
    const float rg = sigmoidf_(g_r + ar + b_r);
    const float zg = sigmoidf_(g_z + az + b_z);
    const float ng = tanhf_(g_n + rg * (an + b_n));
    const float hnew = (1.f - zg) * ng + zg * hp;
    if (lane < 4) {
      unsigned long long* bw = bufU + (size_t)((s + 1) & 1) * HID;
      const unsigned tagv = TAGBASE | (unsigned)(s + 1);
      __hip_atomic_store(bw + uq,
          ((unsigned long long)tagv << 32) | (unsigned long long)__float_as_uint(hnew),
          __ATOMIC_RELAXED, __HIP_MEMORY_SCOPE_AGENT);
    }

    g_r = ng_r; g_z = ng_z; g_n = ng_n;

    __syncthreads();   // protect s_h before next stage-in overwrites it
  }

  // ======================= epilogue + cleanup =======================
  if (blockIdx.x == 0) {
    // stage version 512 (buf0)
    {
      const unsigned wantTag = TAGBASE | (unsigned)SEQ;
      const unsigned long long* br_ = bufU;   // SEQ&1 == 0
      unsigned pending = 0xFFu;
      while (pending) {
        unsigned long long x[8];
        #pragma unroll
        for (int j = 0; j < 8; ++j)
          if (pending & (1u << j))
            x[j] = __hip_atomic_load(br_ + j*256 + tid, __ATOMIC_RELAXED,
                                     __HIP_MEMORY_SCOPE_AGENT);
        #pragma unroll
        for (int j = 0; j < 8; ++j)
          if ((pending & (1u << j)) && (unsigned)(x[j] >> 32) == wantTag) {
            s_h[j*256 + tid] = __uint_as_float((unsigned)x[j]);
            pending &= ~(1u << j);
          }
      }
    }
    __syncthreads();
    if (tid == 0)
      __hip_atomic_store(flag0, 0xD0D0D0D0u, __ATOMIC_RELAXED,
                         __HIP_MEMORY_SCOPE_AGENT);

    // projection + log_softmax from LDS h
    if (wv < 2) {
      const float* wo = wout + (size_t)wv * HID;
      float acc = 0.f;
      #pragma unroll
      for (int c = 0; c < 8; ++c) {
        const float4 h4 = *(const float4*)&s_h[c*256 + lane*4];
        const float4 a4 = *(const float4*)&wo[c*256 + lane*4];
        acc += a4.x*h4.x + a4.y*h4.y + a4.z*h4.z + a4.w*h4.w;
      }
      #pragma unroll
      for (int m = 32; m > 0; m >>= 1) acc += __shfl_xor(acc, m);
      if (lane == 0) s_logits[wv] = acc + bout[wv];
    }
    __syncthreads();
    if (tid == 0) {
      const float l0 = s_logits[0], l1 = s_logits[1];
      const float mx = fmaxf(l0, l1);
      const float lse = mx + logf(expf(l0 - mx) + expf(l1 - mx));
      out[0] = l0 - lse;
      out[1] = l1 - lse;
    }
    // zero own 16 slots in both buffers
    if (tid < 16) {
      const int slot = (tid & 3) + ((tid >> 2) << 9);
      __hip_atomic_store(bufU + slot, 0ull, __ATOMIC_RELAXED, __HIP_MEMORY_SCOPE_AGENT);
      __hip_atomic_store(bufU + HID + slot, 0ull, __ATOMIC_RELAXED, __HIP_MEMORY_SCOPE_AGENT);
    }
    // wait for all other blocks, then zero done[] + flag0
    if (tid >= 1 && tid < NBLK) {
      while (__hip_atomic_load(done + tid * 16, __ATOMIC_RELAXED,
                               __HIP_MEMORY_SCOPE_AGENT) != 0xD1D1D1D1u)
        __builtin_amdgcn_s_sleep(8);
    }
    __syncthreads();
    if (tid < NBLK)
      __hip_atomic_store(done + tid * 16, 0u, __ATOMIC_RELAXED, __HIP_MEMORY_SCOPE_AGENT);
    if (tid == 0)
      __hip_atomic_store(flag0, 0u, __ATOMIC_RELAXED, __HIP_MEMORY_SCOPE_AGENT);
  } else {
    if (tid == 0) {
      while (__hip_atomic_load(flag0, __ATOMIC_RELAXED,
                               __HIP_MEMORY_SCOPE_AGENT) != 0xD0D0D0D0u)
        __builtin_amdgcn_s_sleep(8);
    }
    __syncthreads();
    if (tid < 16) {
      const int slot = blockIdx.x * 4 + (tid & 3) + ((tid >> 2) << 9);
      __hip_atomic_store(bufU + slot, 0ull, __ATOMIC_RELAXED, __HIP_MEMORY_SCOPE_AGENT);
      __hip_atomic_store(bufU + HID + slot, 0ull, __ATOMIC_RELAXED, __HIP_MEMORY_SCOPE_AGENT);
    }
    asm volatile("s_waitcnt vmcnt(0)" ::: "memory");
    __syncthreads();
    if (tid == 0)
      __hip_atomic_store(done + blockIdx.x * 16, 0xD1D1D1D1u, __ATOMIC_RELAXED,
                         __HIP_MEMORY_SCOPE_AGENT);
  }
}

// ---------------------------------------------------------------------------
// Fallback (non-cooperative) path: one kernel per timestep.
// ---------------------------------------------------------------------------
__global__ __launch_bounds__(256) void gru_step_fb(
    const float* __restrict__ GI,
    const float* __restrict__ Whh,
    const float* __restrict__ bhh,
    const int*   __restrict__ inputs, int t,
    const float* __restrict__ h_in,
    float* __restrict__ h_out) {
  const int lane = threadIdx.x & 63;
  const int wvv  = threadIdx.x >> 6;
  const int i = blockIdx.x * 4 + wvv;
  const int v = inputs[t];

  const float4* hv = (const float4*)h_in;
  const float4* wr = (const float4*)(Whh + (size_t)i*HID);
  const float4* wz = (const float4*)(Whh + (size_t)(i+HID)*HID);
  const float4* wn = (const float4*)(Whh + (size_t)(i+2*HID)*HID);

  float ar=0.f, az=0.f, an=0.f;
  #pragma unroll
  for (int c = 0; c < 8; ++c) {
    const int idx = c*64 + lane;
    const float4 h4 = hv[idx];
    float4 a;
    a = wr[idx]; ar += a.x*h4.x + a.y*h4.y + a.z*h4.z + a.w*h4.w;
    a = wz[idx]; az += a.x*h4.x + a.y*h4.y + a.z*h4.z + a.w*h4.w;
    a = wn[idx]; an += a.x*h4.x + a.y*h4.y + a.z*h4.z + a.w*h4.w;
  }
  #pragma unroll
  for (int m = 32; m > 0; m >>= 1) {
    ar += __shfl_xor(ar, m); az += __shfl_xor(az, m); an += __shfl_xor(an, m);
  }
  if (lane == 0) {
    const float* gi = GI + (size_t)v * G3;
    const float r = sigmoidf_(gi[i] + ar + bhh[i]);
    const float z = sigmoidf_(gi[i+HID] + az + bhh[i+HID]);
    const float n = tanhf_(gi[i+2*HID] + r * (an + bhh[i+2*HID]));
    h_out[i] = (1.f - z) * n + z * h_in[i];
  }
}

__global__ void gru_out_fb(const float* __restrict__ h,
                           const float* __restrict__ wout,
                           const float* __restrict__ bout,
                           float* out) {
  __shared__ float logits[2];
  const int lane = threadIdx.x & 63;
  const int wvv  = threadIdx.x >> 6;
  if (wvv < 2) {
    const float4* wo = (const float4*)(wout + (size_t)wvv * HID);
    const float4* hv = (const float4*)h;
    float acc = 0.f;
    #pragma unroll
    for (int c = 0; c < 8; ++c) {
      const int idx = c*64 + lane;
      const float4 a  = wo[idx];
      const float4 h4 = hv[idx];
      acc += a.x*h4.x + a.y*h4.y + a.z*h4.z + a.w*h4.w;
    }
    #pragma unroll
    for (int m = 32; m > 0; m >>= 1) acc += __shfl_xor(acc, m);
    if (lane == 0) logits[wvv] = acc + bout[wvv];
  }
  __syncthreads();
  if (threadIdx.x == 0) {
    const float l0 = logits[0], l1 = logits[1];
    const float mx = fmaxf(l0, l1);
    const float lse = mx + logf(expf(l0 - mx) + expf(l1 - mx));
    out[0] = l0 - lse;
    out[1] = l1 - lse;
  }
}

// ---------------------------------------------------------------------------
extern "C" void kernel_launch(void* const* d_in, const int* in_sizes, int n_in,
                              void* d_out, int out_size, void* d_ws, size_t ws_size,
                              hipStream_t stream) {
  const int*   inputs = (const int*)  d_in[0];
  const float* hx     = (const float*)d_in[1];
  const float* emb    = (const float*)d_in[2];
  const float* w_ih   = (const float*)d_in[3];
  const float* w_hh   = (const float*)d_in[4];
  const float* b_ih   = (const float*)d_in[5];
  const float* b_hh   = (const float*)d_in[6];
  const float* w_out  = (const float*)d_in[7];
  const float* b_out  = (const float*)d_in[8];
  float* out = (float*)d_out;

  float* GI = (float*)d_ws;                                   // 3 MB
  unsigned long long* bufU =
      (unsigned long long*)((char*)d_ws + (size_t)NVOCAB * G3 * 4); // 32 KB
  unsigned* done = (unsigned*)(bufU + 2 * HID);               // (NBLK+1)*16 dw

  gi_precompute<<<dim3(G3/64, NVOCAB/64), 256, 0, stream>>>(emb, w_ih, b_ih, GI);

  void* args[] = { (void*)&GI, (void*)&w_hh, (void*)&b_hh, (void*)&inputs,
                   (void*)&w_out, (void*)&b_out, (void*)&bufU, (void*)&done,
                   (void*)&out, (void*)&hx };
  hipError_t ce = hipLaunchCooperativeKernel((void*)gru_reg, dim3(NBLK), dim3(256),
                                             args, 0, stream);
  if (ce != hipSuccess) {
    float* h0 = (float*)bufU;          // fallback reuses exchange region
    float* h1 = h0 + HID;
    const float* hin = hx;
    for (int t = 0; t < SEQ; ++t) {
      float* hout = (t & 1) ? h1 : h0;
      gru_step_fb<<<512, 256, 0, stream>>>(GI, w_hh, b_hh, inputs, t, hin, hout);
      hin = hout;
    }
    gru_out_fb<<<1, 128, 0, stream>>>(hin, w_out, b_out, out);
  }
}